// Round 6
// baseline (316.042 us; speedup 1.0000x reference)
//
#include <hip/hip_runtime.h>
#include <math.h>

#define B_ 8
#define T_ 64
#define N_ 196
#define D_ 768
#define K_ 8
#define FEAT 40
#define EPSF 1e-6f

constexpr int ROWS = B_ * T_ * N_;                 // 100352
constexpr long long HSIZE = (long long)ROWS * D_;  // 77070336
constexpr int QPR = D_ / 4;                        // 192 float4 per row

typedef float v4f __attribute__((ext_vector_type(4)));

__device__ __forceinline__ float wredux(float v) {
#pragma unroll
    for (int off = 32; off > 0; off >>= 1)
        v += __shfl_xor(v, off, 64);
    return v;
}

__device__ __forceinline__ float dot4(v4f a, v4f b) {
    return a.x * b.x + a.y * b.y + a.z * b.z + a.w * b.w;
}

// W = softplus(W_raw) -> d_out tail;  beta_s = sigmoid(beta) -> ws
__global__ __launch_bounds__(256) void k_wsp(const float* __restrict__ wraw,
                                             const float* __restrict__ beta,
                                             float* __restrict__ wout,
                                             float* __restrict__ beta_s) {
    int i = blockIdx.x * blockDim.x + threadIdx.x;
    if (i < FEAT * D_) {
        float xw = wraw[i];
        wout[i] = fmaxf(xw, 0.0f) + log1pf(expf(-fabsf(xw)));
    }
    if (i < D_) beta_s[i] = 1.0f / (1.0f + expf(-beta[i]));
}

// Fused: one block per (b,n); 1024 threads = 16 waves, wave w owns rows
// t = 4w..4w+3, loaded wave-coalesced (lane-contiguous float4).
// __launch_bounds__(1024,4): 1 block/CU, VGPR ceiling 128 -> x stays in
// registers with NO scratch spills (round-5 failure mode).
__global__ __launch_bounds__(1024, 4) void k_fused(const float* __restrict__ x,
                                                   const float* __restrict__ mask,
                                                   const float* __restrict__ pw,
                                                   const float* __restrict__ wsp,
                                                   const float* __restrict__ beta_s,
                                                   float* __restrict__ h) {
    __shared__ float uld[K_ * D_];        // 24 KB proj_W
    __shared__ float vpart[K_][T_];       // 2 KB   v[k][t]
    __shared__ float sf[FEAT];
    __shared__ float ylds[D_];            // 3 KB   beta_s * y
    __shared__ float smask[T_];

    const int tid  = threadIdx.x;
    const int lane = tid & 63;
    const int w    = tid >> 6;
    const int bn   = blockIdx.x;
    const int b    = bn / N_;
    const int n    = bn - b * N_;

    // stage proj_W (1536 v4f) + mask column
    {
        const v4f* p4 = (const v4f*)pw;
        v4f* u4w = (v4f*)uld;
        if (tid < 768) {
            u4w[tid]       = p4[tid];
            u4w[tid + 768] = p4[tid + 768];
        }
        if (tid < T_) smask[tid] = mask[(b * T_ + tid) * N_ + n];
    }

    // x loads: wave w, rows t=4w+i, lane-contiguous float4 (coalesced 1KB)
    const v4f* x4 = (const v4f*)x;
    unsigned qb[4];
    v4f xr[4][3];
#pragma unroll
    for (int i = 0; i < 4; i++) {
        int t = w * 4 + i;
        qb[i] = (unsigned)(((b * T_ + t) * N_ + n)) * QPR;
#pragma unroll
        for (int c = 0; c < 3; c++)
            xr[i][c] = x4[qb[i] + c * 64 + lane];
    }

    __syncthreads();   // uld, smask ready

    // dots: k-outer so U slice (3 v4f) is loaded once per k
    const v4f* u4 = (const v4f*)uld;
    float acc[4][8];
#pragma unroll
    for (int k = 0; k < K_; k++) {
        v4f u0 = u4[k * 192 + lane];
        v4f u1 = u4[k * 192 + 64 + lane];
        v4f u2 = u4[k * 192 + 128 + lane];
#pragma unroll
        for (int i = 0; i < 4; i++)
            acc[i][k] = dot4(xr[i][0], u0) + dot4(xr[i][1], u1) + dot4(xr[i][2], u2);
    }
#pragma unroll
    for (int i = 0; i < 4; i++) {
#pragma unroll
        for (int k = 0; k < K_; k++)
            acc[i][k] = wredux(acc[i][k]);
        float val = acc[i][0];
#pragma unroll
        for (int k = 1; k < K_; k++)
            val = (lane == k) ? acc[i][k] : val;
        if (lane < K_) vpart[lane][w * 4 + i] = val;
    }
    __syncthreads();

    // stats: wave w<8 owns k=w; lane = t  (validated math)
    if (w < K_) {
        float v = vpart[w][lane] * smask[lane];
        float s2  = wredux(v * v);
        float rms = sqrtf(s2 * (1.0f / T_) + EPSF);
        float vb  = 2.5f * tanhf(v / (rms + EPSF));
        const float PI = 3.14159265358979323846f;
        float ph = PI * ((float)lane + 0.5f) / (float)T_;
        float c1 = cosf(ph), c2 = cosf(2.0f * ph);
        float n1 = wredux(c1 * c1), n2 = wredux(c2 * c2);
        float S1 = wredux(vb), Sc1 = wredux(vb * c1);
        float Sc2 = wredux(vb * c2), Sq = wredux(vb * vb);
        if (lane == 0) {
            float* o = sf + w * 5;
            o[0] = S1 / (8.0f + EPSF);
            o[1] = Sc1 / (sqrtf(n1) + EPSF);
            o[2] = Sc2 / (sqrtf(n2) + EPSF);
            o[3] = S1 * (1.0f / T_);
            o[4] = sqrtf(Sq * (1.0f / T_) + EPSF);
        }
    }
    __syncthreads();

    // tiny GEMM: ylds[d] = beta_s[d] * sum_f sf[f] * wsp[f][d]  (wsp L2-hot)
    if (tid < D_) {
        float a0 = 0.f, a1 = 0.f;
#pragma unroll
        for (int f = 0; f < FEAT; f += 2) {
            a0 += sf[f]     * wsp[f * D_ + tid];
            a1 += sf[f + 1] * wsp[(f + 1) * D_ + tid];
        }
        ylds[tid] = (a0 + a1) * beta_s[tid];
    }
    __syncthreads();

    // h = x + m * ylds, written straight from registers (plain stores)
    const v4f* y4 = (const v4f*)ylds;
    v4f y0 = y4[lane], y1 = y4[64 + lane], y2 = y4[128 + lane];
    v4f* h4 = (v4f*)h;
#pragma unroll
    for (int i = 0; i < 4; i++) {
        float m = smask[w * 4 + i];
        h4[qb[i] + lane]       = xr[i][0] + m * y0;
        h4[qb[i] + 64 + lane]  = xr[i][1] + m * y1;
        h4[qb[i] + 128 + lane] = xr[i][2] + m * y2;
    }
}

extern "C" void kernel_launch(void* const* d_in, const int* in_sizes, int n_in,
                              void* d_out, int out_size, void* d_ws, size_t ws_size,
                              hipStream_t stream) {
    const float* x    = (const float*)d_in[0];
    const float* mask = (const float*)d_in[1];
    const float* pw   = (const float*)d_in[2];
    const float* wraw = (const float*)d_in[3];
    const float* beta = (const float*)d_in[4];

    float* h    = (float*)d_out;
    float* wout = h + HSIZE;
    float* beta_s = (float*)d_ws;   // [768]

    hipLaunchKernelGGL(k_wsp, dim3((FEAT * D_ + 255) / 256), dim3(256), 0, stream,
                       wraw, beta, wout, beta_s);
    hipLaunchKernelGGL(k_fused, dim3(B_ * N_), dim3(1024), 0, stream,
                       x, mask, pw, wout, beta_s, h);
}

// Round 7
// 199.453 us; speedup vs baseline: 1.5845x; 1.5845x over previous
//
#include <hip/hip_runtime.h>
#include <math.h>

#define B_ 8
#define T_ 64
#define N_ 196
#define D_ 768
#define K_ 8
#define FEAT 40
#define EPSF 1e-6f

constexpr int ROWS = B_ * T_ * N_;                 // 100352
constexpr long long HSIZE = (long long)ROWS * D_;  // 77070336
constexpr int QPR = D_ / 4;                        // 192 float4 per row

typedef float v4f __attribute__((ext_vector_type(4)));

__device__ __forceinline__ float wredux(float v) {
#pragma unroll
    for (int off = 32; off > 0; off >>= 1)
        v += __shfl_xor(v, off, 64);
    return v;
}

__device__ __forceinline__ float dot4(v4f a, v4f b) {
    return a.x * b.x + a.y * b.y + a.z * b.z + a.w * b.w;
}

// W = softplus(W_raw) -> d_out tail;  beta_s = sigmoid(beta) -> ws
__global__ __launch_bounds__(256) void k_wsp(const float* __restrict__ wraw,
                                             const float* __restrict__ beta,
                                             float* __restrict__ wout,
                                             float* __restrict__ beta_s) {
    int i = blockIdx.x * blockDim.x + threadIdx.x;
    if (i < FEAT * D_) {
        float xw = wraw[i];
        wout[i] = fmaxf(xw, 0.0f) + log1pf(expf(-fabsf(xw)));
    }
    if (i < D_) beta_s[i] = 1.0f / (1.0f + expf(-beta[i]));
}

// Fused, one block per (b,n), 256 threads = 4 waves.
// Phase A: wave w processes rows t=w*16..w*16+15 ONE AT A TIME (x regs
//   transient, proj_W in 96 VGPRs — round-1-proven register shape).
// Phase B: stats per k (validated math). Phase C: tiny GEMM -> ylds.
// Phase D: reload x (L3-resident, touched ~µs ago), h = x + m*ylds.
__global__ __launch_bounds__(256) void k_fused(const float* __restrict__ x,
                                               const float* __restrict__ mask,
                                               const float* __restrict__ pw,
                                               const float* __restrict__ wsp,
                                               const float* __restrict__ beta_s,
                                               float* __restrict__ h) {
    __shared__ float vpart[T_][K_ + 1];   // +1 pad: odd stride, conflict-free
    __shared__ float sf[FEAT];
    __shared__ float ylds[D_];
    __shared__ float smask[T_];

    const int tid  = threadIdx.x;
    const int lane = tid & 63;
    const int w    = tid >> 6;
    const int bn   = blockIdx.x;
    const int b    = bn / N_;
    const int n    = bn - b * N_;

    // proj_W into registers: u[c][k] covers d = c*256 + lane*4 .. +3
    v4f u[3][K_];
#pragma unroll
    for (int c = 0; c < 3; c++)
#pragma unroll
        for (int k = 0; k < K_; k++)
            u[c][k] = *(const v4f*)(pw + k * D_ + c * 256 + lane * 4);

    if (tid < T_) smask[tid] = mask[(b * T_ + tid) * N_ + n];

    // ---- Phase A ----
    const v4f* x4 = (const v4f*)x;
#pragma unroll 1
    for (int j = 0; j < 16; j++) {
        const int t = w * 16 + j;
        const size_t qb = ((size_t)((b * T_ + t) * N_ + n)) * QPR;
        v4f x0 = x4[qb + lane];
        v4f x1 = x4[qb + 64 + lane];
        v4f x2 = x4[qb + 128 + lane];
        float acc[K_];
#pragma unroll
        for (int k = 0; k < K_; k++)
            acc[k] = dot4(x0, u[0][k]) + dot4(x1, u[1][k]) + dot4(x2, u[2][k]);
        // batched reduce: intra-group(8) butterflies per k
#pragma unroll
        for (int k = 0; k < K_; k++) {
            float a = acc[k];
            a += __shfl_xor(a, 1, 64);
            a += __shfl_xor(a, 2, 64);
            a += __shfl_xor(a, 4, 64);
            acc[k] = a;
        }
        // lane selects k = lane&7, then cross-group reduce (same k aligned)
        const int r = lane & 7;
        float val = (r & 4) ? ((r & 2) ? ((r & 1) ? acc[7] : acc[6])
                                       : ((r & 1) ? acc[5] : acc[4]))
                            : ((r & 2) ? ((r & 1) ? acc[3] : acc[2])
                                       : ((r & 1) ? acc[1] : acc[0]));
        val += __shfl_xor(val, 8, 64);
        val += __shfl_xor(val, 16, 64);
        val += __shfl_xor(val, 32, 64);
        if (lane < K_) vpart[t][lane] = val;
    }
    __syncthreads();

    // ---- Phase B: wave w owns k = w and k = w+4; lane = t ----
#pragma unroll
    for (int kk = 0; kk < 2; kk++) {
        const int k = w + kk * 4;
        float v = vpart[lane][k] * smask[lane];
        float s2  = wredux(v * v);
        float rms = sqrtf(s2 * (1.0f / T_) + EPSF);
        float vb  = 2.5f * tanhf(v / (rms + EPSF));
        const float PI = 3.14159265358979323846f;
        float ph = PI * ((float)lane + 0.5f) / (float)T_;
        float c1 = cosf(ph), c2 = cosf(2.0f * ph);
        float n1 = wredux(c1 * c1), n2 = wredux(c2 * c2);
        float S1 = wredux(vb), Sc1 = wredux(vb * c1);
        float Sc2 = wredux(vb * c2), Sq = wredux(vb * vb);
        if (lane == 0) {
            float* o = sf + k * 5;
            o[0] = S1 / (8.0f + EPSF);
            o[1] = Sc1 / (sqrtf(n1) + EPSF);
            o[2] = Sc2 / (sqrtf(n2) + EPSF);
            o[3] = S1 * (1.0f / T_);
            o[4] = sqrtf(Sq * (1.0f / T_) + EPSF);
        }
    }
    __syncthreads();

    // ---- Phase C: ylds[d] = beta_s[d] * sum_f sf[f]*wsp[f][d] (L2-hot) ----
    for (int d = tid; d < D_; d += 256) {
        float a0 = 0.f, a1 = 0.f;
#pragma unroll
        for (int f = 0; f < FEAT; f += 2) {
            a0 += sf[f]     * wsp[f * D_ + d];
            a1 += sf[f + 1] * wsp[(f + 1) * D_ + d];
        }
        ylds[d] = (a0 + a1) * beta_s[d];
    }
    __syncthreads();

    // ---- Phase D: h = x + m*ylds; x reload hits L3 (just touched) ----
    const v4f* y4 = (const v4f*)ylds;
    v4f* h4 = (v4f*)h;
#pragma unroll 1
    for (int j = 0; j < 16; j++) {
        const int t = w * 16 + j;
        const size_t qb = ((size_t)((b * T_ + t) * N_ + n)) * QPR;
        const float m = smask[t];
        h4[qb + lane]       = x4[qb + lane]       + m * y4[lane];
        h4[qb + 64 + lane]  = x4[qb + 64 + lane]  + m * y4[64 + lane];
        h4[qb + 128 + lane] = x4[qb + 128 + lane] + m * y4[128 + lane];
    }
}

extern "C" void kernel_launch(void* const* d_in, const int* in_sizes, int n_in,
                              void* d_out, int out_size, void* d_ws, size_t ws_size,
                              hipStream_t stream) {
    const float* x    = (const float*)d_in[0];
    const float* mask = (const float*)d_in[1];
    const float* pw   = (const float*)d_in[2];
    const float* wraw = (const float*)d_in[3];
    const float* beta = (const float*)d_in[4];

    float* h    = (float*)d_out;
    float* wout = h + HSIZE;
    float* beta_s = (float*)d_ws;   // [768]

    hipLaunchKernelGGL(k_wsp, dim3((FEAT * D_ + 255) / 256), dim3(256), 0, stream,
                       wraw, beta, wout, beta_s);
    hipLaunchKernelGGL(k_fused, dim3(B_ * N_), dim3(256), 0, stream,
                       x, mask, pw, wout, beta_s, h);
}

// Round 8
// 191.758 us; speedup vs baseline: 1.6481x; 1.0401x over previous
//
#include <hip/hip_runtime.h>
#include <math.h>

#define B_ 8
#define T_ 64
#define N_ 196
#define D_ 768
#define K_ 8
#define FEAT 40
#define EPSF 1e-6f

constexpr int ROWS = B_ * T_ * N_;                 // 100352
constexpr long long HSIZE = (long long)ROWS * D_;  // 77070336
constexpr int QPR = D_ / 4;                        // 192 float4 per row
constexpr size_t RSTRIDE = (size_t)N_ * QPR;       // row stride t->t+1 in v4f

typedef float v4f __attribute__((ext_vector_type(4)));

__device__ __forceinline__ float wredux(float v) {
#pragma unroll
    for (int off = 32; off > 0; off >>= 1)
        v += __shfl_xor(v, off, 64);
    return v;
}

__device__ __forceinline__ float dot4(v4f a, v4f b) {
    return a.x * b.x + a.y * b.y + a.z * b.z + a.w * b.w;
}

// W = softplus(W_raw) -> d_out tail;  beta_s = sigmoid(beta) -> ws
__global__ __launch_bounds__(256) void k_wsp(const float* __restrict__ wraw,
                                             const float* __restrict__ beta,
                                             float* __restrict__ wout,
                                             float* __restrict__ beta_s) {
    int i = blockIdx.x * blockDim.x + threadIdx.x;
    if (i < FEAT * D_) {
        float xw = wraw[i];
        wout[i] = fmaxf(xw, 0.0f) + log1pf(expf(-fabsf(xw)));
    }
    if (i < D_) beta_s[i] = 1.0f / (1.0f + expf(-beta[i]));
}

// Fused, one block per (b,n), 256 threads = 4 waves.
// amdgpu_waves_per_eu(2,3): occupancy target 3 waves/EU -> VGPR budget ~170,
// so proj_W (u[3][8], 96 VGPRs) STAYS IN REGISTERS across phase A
// (round-7 failure: scheduler targeted 8 waves/EU, 72 regs, re-loaded u
// from L1 every row). Phases A and D software-pipelined 2-deep.
__global__ __launch_bounds__(256)
__attribute__((amdgpu_waves_per_eu(2, 3)))
void k_fused(const float* __restrict__ x,
             const float* __restrict__ mask,
             const float* __restrict__ pw,
             const float* __restrict__ wsp,
             const float* __restrict__ beta_s,
             float* __restrict__ h) {
    __shared__ float vpart[T_][K_ + 1];   // +1 pad: odd stride, conflict-free
    __shared__ float sf[FEAT];
    __shared__ float ylds[D_];
    __shared__ float smask[T_];

    const int tid  = threadIdx.x;
    const int lane = tid & 63;
    const int w    = tid >> 6;
    const int bn   = blockIdx.x;
    const int b    = bn / N_;
    const int n    = bn - b * N_;

    // proj_W into registers: u[c][k] covers d = c*256 + lane*4 .. +3
    v4f u[3][K_];
#pragma unroll
    for (int c = 0; c < 3; c++)
#pragma unroll
        for (int k = 0; k < K_; k++)
            u[c][k] = *(const v4f*)(pw + k * D_ + c * 256 + lane * 4);

    if (tid < T_) smask[tid] = mask[(b * T_ + tid) * N_ + n];

    // ---- Phase A: rows t = w*16..w*16+15, 2-deep pipelined ----
    const v4f* x4 = (const v4f*)x;
    size_t qn = ((size_t)((b * T_ + w * 16) * N_ + n)) * QPR;
    v4f n0 = x4[qn + lane];
    v4f n1 = x4[qn + 64 + lane];
    v4f n2 = x4[qn + 128 + lane];
#pragma unroll 1
    for (int j = 0; j < 16; j++) {
        const int t = w * 16 + j;
        v4f c0 = n0, c1 = n1, c2 = n2;
        if (j < 15) {
            qn += RSTRIDE;
            n0 = x4[qn + lane];
            n1 = x4[qn + 64 + lane];
            n2 = x4[qn + 128 + lane];
        }
        float acc[K_];
#pragma unroll
        for (int k = 0; k < K_; k++)
            acc[k] = dot4(c0, u[0][k]) + dot4(c1, u[1][k]) + dot4(c2, u[2][k]);
        // batched reduce: intra-group(8) butterflies per k
#pragma unroll
        for (int k = 0; k < K_; k++) {
            float a = acc[k];
            a += __shfl_xor(a, 1, 64);
            a += __shfl_xor(a, 2, 64);
            a += __shfl_xor(a, 4, 64);
            acc[k] = a;
        }
        // lane selects k = lane&7, then cross-group reduce (same k aligned)
        const int r = lane & 7;
        float val = (r & 4) ? ((r & 2) ? ((r & 1) ? acc[7] : acc[6])
                                       : ((r & 1) ? acc[5] : acc[4]))
                            : ((r & 2) ? ((r & 1) ? acc[3] : acc[2])
                                       : ((r & 1) ? acc[1] : acc[0]));
        val += __shfl_xor(val, 8, 64);
        val += __shfl_xor(val, 16, 64);
        val += __shfl_xor(val, 32, 64);
        if (lane < K_) vpart[t][lane] = val;
    }
    __syncthreads();

    // ---- Phase B: wave w owns k = w and k = w+4; lane = t ----
#pragma unroll
    for (int kk = 0; kk < 2; kk++) {
        const int k = w + kk * 4;
        float v = vpart[lane][k] * smask[lane];
        float s2  = wredux(v * v);
        float rms = sqrtf(s2 * (1.0f / T_) + EPSF);
        float vb  = 2.5f * tanhf(v / (rms + EPSF));
        const float PI = 3.14159265358979323846f;
        float ph = PI * ((float)lane + 0.5f) / (float)T_;
        float c1 = cosf(ph), c2 = cosf(2.0f * ph);
        float n1 = wredux(c1 * c1), n2 = wredux(c2 * c2);
        float S1 = wredux(vb), Sc1 = wredux(vb * c1);
        float Sc2 = wredux(vb * c2), Sq = wredux(vb * vb);
        if (lane == 0) {
            float* o = sf + k * 5;
            o[0] = S1 / (8.0f + EPSF);
            o[1] = Sc1 / (sqrtf(n1) + EPSF);
            o[2] = Sc2 / (sqrtf(n2) + EPSF);
            o[3] = S1 * (1.0f / T_);
            o[4] = sqrtf(Sq * (1.0f / T_) + EPSF);
        }
    }
    __syncthreads();

    // ---- Phase C: ylds[d] = beta_s[d] * sum_f sf[f]*wsp[f][d] (L2-hot) ----
    for (int d = tid; d < D_; d += 256) {
        float a0 = 0.f, a1 = 0.f;
#pragma unroll
        for (int f = 0; f < FEAT; f += 2) {
            a0 += sf[f]     * wsp[f * D_ + d];
            a1 += sf[f + 1] * wsp[(f + 1) * D_ + d];
        }
        ylds[d] = (a0 + a1) * beta_s[d];
    }
    __syncthreads();

    // ---- Phase D: h = x + m*ylds; x reload L3-hot; 2-deep pipelined ----
    const v4f* y4 = (const v4f*)ylds;
    const v4f y0 = y4[lane], y1 = y4[64 + lane], y2 = y4[128 + lane];
    v4f* h4 = (v4f*)h;
    size_t qd = ((size_t)((b * T_ + w * 16) * N_ + n)) * QPR;
    v4f d0 = x4[qd + lane];
    v4f d1 = x4[qd + 64 + lane];
    v4f d2 = x4[qd + 128 + lane];
#pragma unroll 1
    for (int j = 0; j < 16; j++) {
        const int t = w * 16 + j;
        v4f c0 = d0, c1 = d1, c2 = d2;
        const size_t qc = qd;
        if (j < 15) {
            qd += RSTRIDE;
            d0 = x4[qd + lane];
            d1 = x4[qd + 64 + lane];
            d2 = x4[qd + 128 + lane];
        }
        const float m = smask[t];
        h4[qc + lane]       = c0 + m * y0;
        h4[qc + 64 + lane]  = c1 + m * y1;
        h4[qc + 128 + lane] = c2 + m * y2;
    }
}

extern "C" void kernel_launch(void* const* d_in, const int* in_sizes, int n_in,
                              void* d_out, int out_size, void* d_ws, size_t ws_size,
                              hipStream_t stream) {
    const float* x    = (const float*)d_in[0];
    const float* mask = (const float*)d_in[1];
    const float* pw   = (const float*)d_in[2];
    const float* wraw = (const float*)d_in[3];
    const float* beta = (const float*)d_in[4];

    float* h    = (float*)d_out;
    float* wout = h + HSIZE;
    float* beta_s = (float*)d_ws;   // [768]

    hipLaunchKernelGGL(k_wsp, dim3((FEAT * D_ + 255) / 256), dim3(256), 0, stream,
                       wraw, beta, wout, beta_s);
    hipLaunchKernelGGL(k_fused, dim3(B_ * N_), dim3(256), 0, stream,
                       x, mask, pw, wout, beta_s, h);
}